// Round 1
// baseline (21923.756 us; speedup 1.0000x reference)
//
#include <hip/hip_runtime.h>

#define NN 50000
#define NE 800000

__device__ __forceinline__ float siluf(float x){ return x/(1.0f+__expf(-x)); }
__device__ __forceinline__ float sigmf(float x){ return 1.0f/(1.0f+__expf(-x)); }
__device__ __forceinline__ void atomAdd(float* p, float v){ unsafeAtomicAdd(p, v); }

__constant__ const float kC_S  = 0.3826834323650898f;   // sin(pi/8)
__constant__ const float kC_X  = 0.9238795325112867f;   // cos(pi/8)
#define C_S 0.3826834323650898f
#define C_X 0.9238795325112867f
#define RS10 0.31622776601683794f   // 1/sqrt(10)
#define RS16 0.25f                  // 1/sqrt(16)
#define RS32 0.1767766952966369f    // 1/sqrt(32)
#define RS48 0.14433756729740643f   // 1/sqrt(48)
#define SR2  0.1f                   // 1/sqrt(100)
#define ISQ3 0.5773502691896258f
#define SQ3F 1.7320508075688772f
#define ISNN 0.25f                  // 1/sqrt(16)
#define EMBS 2.8234621965789103f    // sqrt(10)/1.12
#define PIF  3.14159265358979323846f

// ---------------------------------------------------------------- embed
__global__ void k_embed(const float* __restrict__ oh, const float* __restrict__ W,
                        const float* __restrict__ b, float* __restrict__ xs)
{
    __shared__ float lw[118*16];
    __shared__ float lb[16];
    for (int i = threadIdx.x; i < 118*16; i += blockDim.x) lw[i] = W[i];
    if (threadIdx.x < 16) lb[threadIdx.x] = b[threadIdx.x];
    __syncthreads();
    int n = blockIdx.x*blockDim.x + threadIdx.x;
    if (n >= NN) return;
    float acc[16];
#pragma unroll
    for (int j = 0; j < 16; ++j) acc[j] = lb[j];
    for (int i = 0; i < 118; ++i) {
        float o = oh[n*118 + i];
#pragma unroll
        for (int j = 0; j < 16; ++j) acc[j] += o*lw[i*16 + j];
    }
#pragma unroll
    for (int j = 0; j < 16; ++j) xs[n*48 + j] = acc[j];
}

// ---------------------------------------------------------------- node pre-linear
template<int SIN, int SOUT, int V>
__global__ void k_pre(const float* __restrict__ xs, const float* __restrict__ xv,
                      const float* __restrict__ Ws, const float* __restrict__ Wv,
                      float* __restrict__ xs1, float* __restrict__ xv1,
                      float ss, float sv)
{
    __shared__ float lws[SIN*SOUT];
    __shared__ float lwv[(V > 0) ? 256 : 1];
    for (int i = threadIdx.x; i < SIN*SOUT; i += blockDim.x) lws[i] = Ws[i];
    if constexpr (V > 0)
        for (int i = threadIdx.x; i < 256; i += blockDim.x) lwv[i] = Wv[i];
    __syncthreads();
    int n = blockIdx.x*blockDim.x + threadIdx.x;
    if (n >= NN) return;
    float xr[SIN];
#pragma unroll
    for (int u = 0; u < SIN; ++u) xr[u] = xs[n*48 + u];
#pragma unroll
    for (int j = 0; j < SOUT; ++j) {
        float a = 0.f;
#pragma unroll
        for (int u = 0; u < SIN; ++u) a += xr[u]*lws[u*SOUT + j];
        xs1[n*SOUT + j] = a*ss;
    }
    if constexpr (V > 0) {
        float vr[48];
#pragma unroll
        for (int i = 0; i < 48; ++i) vr[i] = xv[n*48 + i];
#pragma unroll
        for (int w = 0; w < 16; ++w) {
            float a0 = 0.f, a1 = 0.f, a2 = 0.f;
#pragma unroll
            for (int v = 0; v < 16; ++v) {
                float wt = lwv[v*16 + w];
                a0 += vr[v*3+0]*wt; a1 += vr[v*3+1]*wt; a2 += vr[v*3+2]*wt;
            }
            xv1[n*48 + w*3 + 0] = a0*sv;
            xv1[n*48 + w*3 + 1] = a1*sv;
            xv1[n*48 + w*3 + 2] = a2*sv;
        }
    }
}

// ---------------------------------------------------------------- fused edge kernel
// Per edge: recompute geometry, h = silu(emb@R1 * RS10) in regs,
// stream w = h@R2 * SR2 from LDS chunks, scatter messages via atomics.
template<int S, int V, int WOUT, bool VEC_OUT, int NCHUNK>
__global__ void __launch_bounds__(256) k_edge(
    const float* __restrict__ pos, const float* __restrict__ ea,
    const int* __restrict__ srcv, const int* __restrict__ dstv,
    const float* __restrict__ xs1, const float* __restrict__ xv1,
    const float* __restrict__ R1, const float* __restrict__ R2,
    float* __restrict__ ys, float* __restrict__ yv)
{
    constexpr int CHUNK = 80;
    constexpr int O1 = S*4;
    constexpr int O2 = VEC_OUT ? O1 + S : O1;
    constexpr int O3 = (VEC_OUT && V > 0) ? O2 + V*4 : O2;
    __shared__ __align__(16) float lR1[100*12];
    __shared__ __align__(16) float lR2[100*CHUNK];
    for (int idx = threadIdx.x; idx < 1000; idx += 256) {
        int i = idx/100, k = idx%100;
        lR1[k*12 + i] = R1[idx];            // transposed: [k][i]
    }
    const int e = blockIdx.x*256 + threadIdx.x;
    const bool valid = (e < NE);
    int src = 0, dst = 0;
    float es0=0,es1=0,es2=0,es3=0, ev0=0,ev1=0,ev2=0;
    float eb0=0,eb1=0,eb2=0,eb3=0,eb4=0,eb5=0,eb6=0,eb7=0,eb8=0,eb9=0;
    if (valid) {
        src = srcv[e]; dst = dstv[e];
        float vx = pos[3*src+0] - pos[3*dst+0];
        float vy = pos[3*src+1] - pos[3*dst+1];
        float vz = pos[3*src+2] - pos[3*dst+2];
        float r  = sqrtf(vx*vx + vy*vy + vz*vz + 1e-12f);
        float ir = 1.0f/r;
        float uu = 2.0f*(r*(1.0f/3.5f) - 1.0f);
        float cut = (uu > 0.0f) ? 0.0f
                  : ((uu < -1.0f) ? 1.0f : 0.5f*(1.0f - cosf(PIF*uu)));
        es0 = ea[3*e+0]; es1 = ea[3*e+1]; es2 = ea[3*e+2]; es3 = cut;
        float cs = cut*SQ3F*ir;
        ev0 = cs*vx; ev1 = cs*vy; ev2 = cs*vz;
        float q = r*2.5714285714285716f;   // r/step, step=3.5/9
        float t;
        t=q-0.f; eb0=__expf(-t*t)*EMBS;  t=q-1.f; eb1=__expf(-t*t)*EMBS;
        t=q-2.f; eb2=__expf(-t*t)*EMBS;  t=q-3.f; eb3=__expf(-t*t)*EMBS;
        t=q-4.f; eb4=__expf(-t*t)*EMBS;  t=q-5.f; eb5=__expf(-t*t)*EMBS;
        t=q-6.f; eb6=__expf(-t*t)*EMBS;  t=q-7.f; eb7=__expf(-t*t)*EMBS;
        t=q-8.f; eb8=__expf(-t*t)*EMBS;  t=q-9.f; eb9=__expf(-t*t)*EMBS;
    }
    __syncthreads();
    float h[100];
#pragma unroll
    for (int k = 0; k < 100; ++k) {
        const float4 w0 = *(const float4*)&lR1[k*12];
        const float4 w1 = *(const float4*)&lR1[k*12 + 4];
        const float2 w2 = *(const float2*)&lR1[k*12 + 8];
        float a = eb0*w0.x + eb1*w0.y + eb2*w0.z + eb3*w0.w
                + eb4*w1.x + eb5*w1.y + eb6*w1.z + eb7*w1.w
                + eb8*w2.x + eb9*w2.y;
        h[k] = siluf(a*RS10);
    }
    const float* xsrow = xs1 + (size_t)src*S;
    const float* xvrow = xv1 + (size_t)src*48;
    float* ysrow = ys + (size_t)dst*48;
    float* yvrow = yv + (size_t)dst*144;
#pragma unroll 1
    for (int ch = 0; ch < NCHUNK; ++ch) {
        const int c0 = ch*CHUNK;
        const int cw = (WOUT - c0) < CHUNK ? (WOUT - c0) : CHUNK;
        __syncthreads();
        for (int idx = threadIdx.x; idx < 100*cw; idx += 256) {
            int k = idx/cw, j = idx%cw;
            lR2[k*CHUNK + j] = R2[k*WOUT + c0 + j];
        }
        __syncthreads();
#pragma unroll 1
        for (int g = 0; g < cw/4; ++g) {
            const int j0 = c0 + 4*g;
            float4 LA = {0,0,0,0}, LB = {0,0,0,0}, LC = {0,0,0,0};
            if (valid) {                        // pre-issue operand gathers
                if (j0 < O1)                      { LA.x = xsrow[j0 >> 2]; }
                else if (VEC_OUT && j0 < O2)      { LA = *(const float4*)(xsrow + (j0 - O1)); }
                else if (V > 0 && VEC_OUT && j0 < O3) {
                    int u2 = (j0 - O2) >> 2;
                    LA.x = xvrow[u2*3]; LA.y = xvrow[u2*3+1]; LA.z = xvrow[u2*3+2];
                } else if (V > 0) {
                    const float4* pv = (const float4*)(xvrow + (j0 - O3)*3);
                    LA = pv[0]; LB = pv[1]; LC = pv[2];
                }
            }
            float a0=0.f, a1=0.f, a2=0.f, a3=0.f;
#pragma unroll
            for (int k = 0; k < 100; ++k) {
                const float4 w = *(const float4*)&lR2[k*CHUNK + 4*g];
                a0 += h[k]*w.x; a1 += h[k]*w.y; a2 += h[k]*w.z; a3 += h[k]*w.w;
            }
            a0 *= SR2; a1 *= SR2; a2 *= SR2; a3 *= SR2;
            if (valid) {
                if (j0 < O1) {                                    // w1: scalar msg
                    float dv = a0*es0 + a1*es1 + a2*es2 + a3*es3;
                    atomAdd(ysrow + (j0 >> 2), 0.5f*LA.x*dv);
                } else if (VEC_OUT && j0 < O2) {                  // w2: s->v msg
                    int u0 = j0 - O1;
                    float m0 = LA.x*a0, m1 = LA.y*a1, m2 = LA.z*a2, m3 = LA.w*a3;
                    atomAdd(yvrow+(u0+0)*3+0, m0*ev0); atomAdd(yvrow+(u0+0)*3+1, m0*ev1); atomAdd(yvrow+(u0+0)*3+2, m0*ev2);
                    atomAdd(yvrow+(u0+1)*3+0, m1*ev0); atomAdd(yvrow+(u0+1)*3+1, m1*ev1); atomAdd(yvrow+(u0+1)*3+2, m1*ev2);
                    atomAdd(yvrow+(u0+2)*3+0, m2*ev0); atomAdd(yvrow+(u0+2)*3+1, m2*ev1); atomAdd(yvrow+(u0+2)*3+2, m2*ev2);
                    atomAdd(yvrow+(u0+3)*3+0, m3*ev0); atomAdd(yvrow+(u0+3)*3+1, m3*ev1); atomAdd(yvrow+(u0+3)*3+2, m3*ev2);
                } else if (V > 0 && VEC_OUT && j0 < O3) {         // w3: v->v msg
                    int u2 = (j0 - O2) >> 2;
                    float dv = (a0*es0 + a1*es1 + a2*es2 + a3*es3)*0.5f;
                    atomAdd(yvrow+(S+u2)*3+0, dv*LA.x);
                    atomAdd(yvrow+(S+u2)*3+1, dv*LA.y);
                    atomAdd(yvrow+(S+u2)*3+2, dv*LA.z);
                } else if (V > 0) {                               // w4: v->s msg
                    int u0 = j0 - O3;
                    float d0 = LA.x*ev0 + LA.y*ev1 + LA.z*ev2;
                    float d1 = LA.w*ev0 + LB.x*ev1 + LB.y*ev2;
                    float d2 = LB.z*ev0 + LB.w*ev1 + LC.x*ev2;
                    float d3 = LC.y*ev0 + LC.z*ev1 + LC.w*ev2;
                    atomAdd(ysrow+S+u0+0, a0*d0*ISQ3);
                    atomAdd(ysrow+S+u0+1, a1*d1*ISQ3);
                    atomAdd(ysrow+S+u0+2, a2*d2*ISQ3);
                    atomAdd(ysrow+S+u0+3, a3*d3*ISQ3);
                }
            }
        }
    }
}

// ---------------------------------------------------------------- node post + gate (in-place)
template<int SIN, int YSW, int M, bool HASV>
__global__ void k_post(float* __restrict__ xsv, float* __restrict__ xvv,
                       const float* __restrict__ ys, const float* __restrict__ yv,
                       const float* __restrict__ scs, const float* __restrict__ scv,
                       const float* __restrict__ l2s, const float* __restrict__ l2v,
                       float s_sc, float s_l2s, float s_scv, float s_l2v)
{
    __shared__ float Lscs[SIN*48];
    __shared__ float Ll2s[YSW*48];
    __shared__ float Lscv[HASV ? 256 : 1];
    __shared__ float Ll2v[M*16];
    for (int i = threadIdx.x; i < SIN*48; i += blockDim.x) Lscs[i] = scs[i];
    for (int i = threadIdx.x; i < YSW*48; i += blockDim.x) Ll2s[i] = l2s[i];
    if constexpr (HASV)
        for (int i = threadIdx.x; i < 256; i += blockDim.x) Lscv[i] = scv[i];
    for (int i = threadIdx.x; i < M*16; i += blockDim.x) Ll2v[i] = l2v[i];
    __syncthreads();
    int n = blockIdx.x*blockDim.x + threadIdx.x;
    if (n >= NN) return;
    float xr[SIN];
#pragma unroll
    for (int u = 0; u < SIN; ++u) xr[u] = xsv[n*48 + u];
    float yr[YSW];
#pragma unroll
    for (int t = 0; t < YSW; ++t) yr[t] = ys[n*48 + t]*ISNN;
    float os[48];
    const float A = C_S*s_sc, B = C_X*s_l2s;
#pragma unroll
    for (int j = 0; j < 48; ++j) {
        float a = 0.f, b = 0.f;
#pragma unroll
        for (int u = 0; u < SIN; ++u) a += xr[u]*Lscs[u*48 + j];
#pragma unroll
        for (int t = 0; t < YSW; ++t) b += yr[t]*Ll2s[t*48 + j];
        os[j] = A*a + B*b;
    }
#pragma unroll
    for (int u = 0; u < 32; ++u) xsv[n*48 + u] = siluf(os[u]);
    float gg[16];
#pragma unroll
    for (int t = 0; t < 16; ++t) gg[t] = sigmf(os[32 + t]);
    // vector channel: out_v = [C_S*sc_v +] Bv * linv(yv)
    float a0[16], a1[16], a2[16];
#pragma unroll
    for (int w = 0; w < 16; ++w) { a0[w]=0.f; a1[w]=0.f; a2[w]=0.f; }
#pragma unroll
    for (int m = 0; m < M; ++m) {
        float y0 = yv[n*144 + m*3 + 0]*ISNN;
        float y1 = yv[n*144 + m*3 + 1]*ISNN;
        float y2 = yv[n*144 + m*3 + 2]*ISNN;
#pragma unroll
        for (int w = 0; w < 16; ++w) {
            float wt = Ll2v[m*16 + w];
            a0[w] += y0*wt; a1[w] += y1*wt; a2[w] += y2*wt;
        }
    }
    const float Bv = HASV ? (C_X*s_l2v) : s_l2v;   // layer1: out_v = yv (no C_X, no sc)
    if constexpr (HASV) {
        float vr[48];
#pragma unroll
        for (int i = 0; i < 48; ++i) vr[i] = xvv[n*48 + i];
        const float Av = C_S*s_scv;
#pragma unroll
        for (int w = 0; w < 16; ++w) {
            float s0 = 0.f, s1 = 0.f, s2 = 0.f;
#pragma unroll
            for (int v = 0; v < 16; ++v) {
                float wt = Lscv[v*16 + w];
                s0 += vr[v*3+0]*wt; s1 += vr[v*3+1]*wt; s2 += vr[v*3+2]*wt;
            }
            xvv[n*48 + w*3 + 0] = (Av*s0 + Bv*a0[w])*gg[w];
            xvv[n*48 + w*3 + 1] = (Av*s1 + Bv*a1[w])*gg[w];
            xvv[n*48 + w*3 + 2] = (Av*s2 + Bv*a2[w])*gg[w];
        }
    } else {
#pragma unroll
        for (int w = 0; w < 16; ++w) {
            xvv[n*48 + w*3 + 0] = Bv*a0[w]*gg[w];
            xvv[n*48 + w*3 + 1] = Bv*a1[w]*gg[w];
            xvv[n*48 + w*3 + 2] = Bv*a2[w]*gg[w];
        }
    }
}

// ---------------------------------------------------------------- layer4 post + head
__global__ void k_final(const float* __restrict__ xsv, const float* __restrict__ ys,
                        const float* __restrict__ scs, const float* __restrict__ l2s,
                        const float* __restrict__ Wh, const float* __restrict__ bh,
                        float* __restrict__ out)
{
    __shared__ float Lscs[32*8];
    __shared__ float Ll2s[48*8];
    __shared__ float Lwh[24];
    __shared__ float Lbh[3];
    for (int i = threadIdx.x; i < 32*8; i += blockDim.x) Lscs[i] = scs[i];
    for (int i = threadIdx.x; i < 48*8; i += blockDim.x) Ll2s[i] = l2s[i];
    if (threadIdx.x < 24) Lwh[threadIdx.x] = Wh[threadIdx.x];
    if (threadIdx.x < 3)  Lbh[threadIdx.x] = bh[threadIdx.x];
    __syncthreads();
    int n = blockIdx.x*blockDim.x + threadIdx.x;
    if (n >= NN) return;
    float xr[32];
#pragma unroll
    for (int u = 0; u < 32; ++u) xr[u] = xsv[n*48 + u];
    float yr[48];
#pragma unroll
    for (int t = 0; t < 48; ++t) yr[t] = ys[n*48 + t]*ISNN;
    float s8[8];
#pragma unroll
    for (int j = 0; j < 8; ++j) {
        float a = 0.f, b = 0.f;
#pragma unroll
        for (int u = 0; u < 32; ++u) a += xr[u]*Lscs[u*8 + j];
#pragma unroll
        for (int t = 0; t < 48; ++t) b += yr[t]*Ll2s[t*8 + j];
        s8[j] = C_S*RS32*a + C_X*RS48*b;
    }
#pragma unroll
    for (int c = 0; c < 3; ++c) {
        float o = Lbh[c];
#pragma unroll
        for (int j = 0; j < 8; ++j) o += s8[j]*Lwh[j*3 + c];
        out[n*3 + c] = o;
    }
}

// ---------------------------------------------------------------- launcher
extern "C" void kernel_launch(void* const* d_in, const int* in_sizes, int n_in,
                              void* d_out, int out_size, void* d_ws, size_t ws_size,
                              hipStream_t stream)
{
    const float* pos       = (const float*)d_in[0];
    const float* onehot    = (const float*)d_in[1];
    const float* eattr     = (const float*)d_in[2];
    const float* W_embed   = (const float*)d_in[3];
    const float* b_embed   = (const float*)d_in[4];
    const float* l1_lin1_s = (const float*)d_in[5];
    const float* l1_sc_s   = (const float*)d_in[6];
    const float* l1_R1     = (const float*)d_in[7];
    const float* l1_R2     = (const float*)d_in[8];
    const float* l1_lin2_s = (const float*)d_in[9];
    const float* l1_lin2_v = (const float*)d_in[10];
    const float* l2_lin1_s = (const float*)d_in[11];
    const float* l2_lin1_v = (const float*)d_in[12];
    const float* l2_sc_s   = (const float*)d_in[13];
    const float* l2_sc_v   = (const float*)d_in[14];
    const float* l2_R1     = (const float*)d_in[15];
    const float* l2_R2     = (const float*)d_in[16];
    const float* l2_lin2_s = (const float*)d_in[17];
    const float* l2_lin2_v = (const float*)d_in[18];
    const float* l3_lin1_s = (const float*)d_in[19];
    const float* l3_lin1_v = (const float*)d_in[20];
    const float* l3_sc_s   = (const float*)d_in[21];
    const float* l3_sc_v   = (const float*)d_in[22];
    const float* l3_R1     = (const float*)d_in[23];
    const float* l3_R2     = (const float*)d_in[24];
    const float* l3_lin2_s = (const float*)d_in[25];
    const float* l3_lin2_v = (const float*)d_in[26];
    const float* l4_lin1_s = (const float*)d_in[27];
    const float* l4_lin1_v = (const float*)d_in[28];
    const float* l4_sc_s   = (const float*)d_in[29];
    const float* l4_R1     = (const float*)d_in[30];
    const float* l4_R2     = (const float*)d_in[31];
    const float* l4_lin2_s = (const float*)d_in[32];
    const float* W_head    = (const float*)d_in[33];
    const float* b_head    = (const float*)d_in[34];
    const int*   eidx      = (const int*)d_in[35];
    const int* srcv = eidx;
    const int* dstv = eidx + NE;

    float* ws = (float*)d_ws;
    size_t off = 0;
    float* XS  = ws + off; off += 48ull*NN;
    float* XV  = ws + off; off += 48ull*NN;
    float* XS1 = ws + off; off += 32ull*NN;
    float* XV1 = ws + off; off += 48ull*NN;
    float* YS  = ws + off; off += 48ull*NN;   // YS and YV contiguous: one memset
    float* YV  = ws + off; off += 144ull*NN;

    dim3 th(256), be((NE + 255)/256), bn((NN + 255)/256);

    k_embed<<<bn, th, 0, stream>>>(onehot, W_embed, b_embed, XS);

    // ---- layer 1 (S=16, V=0, WOUT=80, vec_out)
    k_pre<16,16,0><<<bn, th, 0, stream>>>(XS, nullptr, l1_lin1_s, nullptr, XS1, XV1, RS16, RS16);
    hipMemsetAsync(YS, 0, (48ull+144ull)*NN*sizeof(float), stream);
    k_edge<16,0,80,true,1><<<be, th, 0, stream>>>(pos, eattr, srcv, dstv, XS1, XV1, l1_R1, l1_R2, YS, YV);
    k_post<16,16,16,false><<<bn, th, 0, stream>>>(XS, XV, YS, YV, l1_sc_s, nullptr, l1_lin2_s, l1_lin2_v,
                                                  RS16, RS16, 0.f, RS16);

    // ---- layer 2 (S=32, V=16, WOUT=240, vec_out)
    k_pre<32,32,16><<<bn, th, 0, stream>>>(XS, XV, l2_lin1_s, l2_lin1_v, XS1, XV1, RS32, RS16);
    hipMemsetAsync(YS, 0, (48ull+144ull)*NN*sizeof(float), stream);
    k_edge<32,16,240,true,3><<<be, th, 0, stream>>>(pos, eattr, srcv, dstv, XS1, XV1, l2_R1, l2_R2, YS, YV);
    k_post<32,48,48,true><<<bn, th, 0, stream>>>(XS, XV, YS, YV, l2_sc_s, l2_sc_v, l2_lin2_s, l2_lin2_v,
                                                 RS32, RS48, RS16, RS48);

    // ---- layer 3 (same shapes as layer 2)
    k_pre<32,32,16><<<bn, th, 0, stream>>>(XS, XV, l3_lin1_s, l3_lin1_v, XS1, XV1, RS32, RS16);
    hipMemsetAsync(YS, 0, (48ull+144ull)*NN*sizeof(float), stream);
    k_edge<32,16,240,true,3><<<be, th, 0, stream>>>(pos, eattr, srcv, dstv, XS1, XV1, l3_R1, l3_R2, YS, YV);
    k_post<32,48,48,true><<<bn, th, 0, stream>>>(XS, XV, YS, YV, l3_sc_s, l3_sc_v, l3_lin2_s, l3_lin2_v,
                                                 RS32, RS48, RS16, RS48);

    // ---- layer 4 (S=32, V=16, WOUT=144, no vec_out) + head
    k_pre<32,32,16><<<bn, th, 0, stream>>>(XS, XV, l4_lin1_s, l4_lin1_v, XS1, XV1, RS32, RS16);
    hipMemsetAsync(YS, 0, 48ull*NN*sizeof(float), stream);
    k_edge<32,16,144,false,2><<<be, th, 0, stream>>>(pos, eattr, srcv, dstv, XS1, XV1, l4_R1, l4_R2, YS, YV);
    k_final<<<bn, th, 0, stream>>>(XS, YS, l4_sc_s, l4_lin2_s, W_head, b_head, (float*)d_out);
}

// Round 2
// 8077.058 us; speedup vs baseline: 2.7143x; 2.7143x over previous
//
#include <hip/hip_runtime.h>

#define NN 50000
#define NE 800000

__device__ __forceinline__ float siluf(float x){ return x/(1.0f+__expf(-x)); }
__device__ __forceinline__ float sigmf(float x){ return 1.0f/(1.0f+__expf(-x)); }

#define C_S 0.3826834323650898f
#define C_X 0.9238795325112867f
#define RS10 0.31622776601683794f   // 1/sqrt(10)
#define RS16 0.25f                  // 1/sqrt(16)
#define RS32 0.1767766952966369f    // 1/sqrt(32)
#define RS48 0.14433756729740643f   // 1/sqrt(48)
#define SR2  0.1f                   // 1/sqrt(100)
#define ISQ3 0.5773502691896258f
#define SQ3F 1.7320508075688772f
#define ISNN 0.25f                  // 1/sqrt(16)
#define EMBS 2.8234621965789103f    // sqrt(10)/1.12
#define PIF  3.14159265358979323846f

// ---------------------------------------------------------------- embed
__global__ void k_embed(const float* __restrict__ oh, const float* __restrict__ W,
                        const float* __restrict__ b, float* __restrict__ xs)
{
    __shared__ float lw[118*16];
    __shared__ float lb[16];
    for (int i = threadIdx.x; i < 118*16; i += blockDim.x) lw[i] = W[i];
    if (threadIdx.x < 16) lb[threadIdx.x] = b[threadIdx.x];
    __syncthreads();
    int n = blockIdx.x*blockDim.x + threadIdx.x;
    if (n >= NN) return;
    float acc[16];
#pragma unroll
    for (int j = 0; j < 16; ++j) acc[j] = lb[j];
    for (int i = 0; i < 118; ++i) {
        float o = oh[n*118 + i];
#pragma unroll
        for (int j = 0; j < 16; ++j) acc[j] += o*lw[i*16 + j];
    }
#pragma unroll
    for (int j = 0; j < 16; ++j) xs[n*48 + j] = acc[j];
}

// ---------------------------------------------------------------- sort build
__global__ void k_hist(const int* __restrict__ dstv, int* __restrict__ cursor)
{
    int e = blockIdx.x*blockDim.x + threadIdx.x;
    if (e < NE) atomicAdd(&cursor[dstv[e]], 1);
}

__global__ void k_scan(int* __restrict__ cnt, int* __restrict__ start)
{
    __shared__ int part[1024];
    const int L = (NN + 1023)/1024;
    int t = threadIdx.x;
    int b0 = t*L, b1 = b0 + L; if (b1 > NN) b1 = NN; if (b0 > NN) b0 = NN;
    int s = 0;
    for (int i = b0; i < b1; ++i) s += cnt[i];
    part[t] = s;
    __syncthreads();
    for (int off = 1; off < 1024; off <<= 1) {
        int vv = (t >= off) ? part[t-off] : 0;
        __syncthreads();
        part[t] += vv;
        __syncthreads();
    }
    int run = (t == 0) ? 0 : part[t-1];
    for (int i = b0; i < b1; ++i) {
        int cc = cnt[i];
        start[i] = run;
        cnt[i] = run;      // cursor re-initialized to start for scatter pass
        run += cc;
    }
    if (t == 1023) start[NN] = part[1023];
}

__global__ void k_scatter(const int* __restrict__ dstv, int* __restrict__ cursor,
                          int* __restrict__ perm)
{
    int e = blockIdx.x*blockDim.x + threadIdx.x;
    if (e < NE) {
        int p = atomicAdd(&cursor[dstv[e]], 1);
        perm[p] = e;
    }
}

// ---------------------------------------------------------------- node pre-linear
template<int SIN, int SOUT, int V>
__global__ void k_pre(const float* __restrict__ xs, const float* __restrict__ xv,
                      const float* __restrict__ Ws, const float* __restrict__ Wv,
                      float* __restrict__ xs1, float* __restrict__ xv1,
                      float ss, float sv)
{
    __shared__ float lws[SIN*SOUT];
    __shared__ float lwv[(V > 0) ? 256 : 1];
    for (int i = threadIdx.x; i < SIN*SOUT; i += blockDim.x) lws[i] = Ws[i];
    if constexpr (V > 0)
        for (int i = threadIdx.x; i < 256; i += blockDim.x) lwv[i] = Wv[i];
    __syncthreads();
    int n = blockIdx.x*blockDim.x + threadIdx.x;
    if (n >= NN) return;
    float xr[SIN];
#pragma unroll
    for (int u = 0; u < SIN; ++u) xr[u] = xs[n*48 + u];
#pragma unroll
    for (int j = 0; j < SOUT; ++j) {
        float a = 0.f;
#pragma unroll
        for (int u = 0; u < SIN; ++u) a += xr[u]*lws[u*SOUT + j];
        xs1[n*SOUT + j] = a*ss;
    }
    if constexpr (V > 0) {
        float vr[48];
#pragma unroll
        for (int i = 0; i < 48; ++i) vr[i] = xv[n*48 + i];
#pragma unroll
        for (int w = 0; w < 16; ++w) {
            float a0 = 0.f, a1 = 0.f, a2 = 0.f;
#pragma unroll
            for (int v = 0; v < 16; ++v) {
                float wt = lwv[v*16 + w];
                a0 += vr[v*3+0]*wt; a1 += vr[v*3+1]*wt; a2 += vr[v*3+2]*wt;
            }
            xv1[n*48 + w*3 + 0] = a0*sv;
            xv1[n*48 + w*3 + 1] = a1*sv;
            xv1[n*48 + w*3 + 2] = a2*sv;
        }
    }
}

// ---------------------------------------------------------------- edge message kernel
// Processes sorted positions p in [p0,p1): e = perm[p]. Computes the per-edge
// filter MLP and writes a compact message row msg[p-p0][WM] (no atomics).
// For VEC_OUT layers, lin2_v (M x 16) is folded in: vec part is 16x3 floats.
// For FOLD (layer4), lin2_s (48 x 8) is folded in: row is just 8 floats.
template<int S,int V,int WOUT,bool VEC_OUT,int NCH,int WM,int WMS,bool FOLD>
__global__ void __launch_bounds__(256) k_edgemsg(
    const float* __restrict__ pos, const float* __restrict__ ea,
    const int* __restrict__ srcv, const int* __restrict__ dstv,
    const int* __restrict__ perm,
    const float* __restrict__ xs1, const float* __restrict__ xv1,
    const float* __restrict__ R1, const float* __restrict__ R2,
    const float* __restrict__ WF, float* __restrict__ msg, int p0, int p1)
{
    constexpr int CHUNK = 80;
    constexpr int O1 = S*4;
    constexpr int O2 = VEC_OUT ? O1 + S : O1;
    constexpr int O3 = (VEC_OUT && V > 0) ? O2 + V*4 : O2;
    constexpr int NF = FOLD ? (S+V)*8 : (VEC_OUT ? (S+V)*16 : 0);
    __shared__ __align__(16) float lR1[1200];
    __shared__ __align__(16) float lR2[100*CHUNK];
    __shared__ float lWF[(NF > 0) ? NF : 1];
    for (int idx = threadIdx.x; idx < 1000; idx += 256) {
        int i = idx/100, k = idx%100;
        lR1[k*12 + i] = R1[idx];            // transposed: [k][i]
    }
    if constexpr (NF > 0)
        for (int i = threadIdx.x; i < NF; i += 256) lWF[i] = WF[i];

    const int p = p0 + blockIdx.x*256 + threadIdx.x;
    const bool valid = (p < p1);
    const int e = valid ? perm[p] : 0;
    int src = 0, dst = 0;
    float es0=0,es1=0,es2=0,es3=0, ev0=0,ev1=0,ev2=0;
    float eb0=0,eb1=0,eb2=0,eb3=0,eb4=0,eb5=0,eb6=0,eb7=0,eb8=0,eb9=0;
    if (valid) {
        src = srcv[e]; dst = dstv[e];
        float vx = pos[3*src+0] - pos[3*dst+0];
        float vy = pos[3*src+1] - pos[3*dst+1];
        float vz = pos[3*src+2] - pos[3*dst+2];
        float r  = sqrtf(vx*vx + vy*vy + vz*vz + 1e-12f);
        float ir = 1.0f/r;
        float uu = 2.0f*(r*(1.0f/3.5f) - 1.0f);
        float cut = (uu > 0.0f) ? 0.0f
                  : ((uu < -1.0f) ? 1.0f : 0.5f*(1.0f - cosf(PIF*uu)));
        es0 = ea[3*e+0]; es1 = ea[3*e+1]; es2 = ea[3*e+2]; es3 = cut;
        float cs = cut*SQ3F*ir;
        ev0 = cs*vx; ev1 = cs*vy; ev2 = cs*vz;
        float q = r*2.5714285714285716f;   // r/step, step=3.5/9
        float t;
        t=q-0.f; eb0=__expf(-t*t)*EMBS;  t=q-1.f; eb1=__expf(-t*t)*EMBS;
        t=q-2.f; eb2=__expf(-t*t)*EMBS;  t=q-3.f; eb3=__expf(-t*t)*EMBS;
        t=q-4.f; eb4=__expf(-t*t)*EMBS;  t=q-5.f; eb5=__expf(-t*t)*EMBS;
        t=q-6.f; eb6=__expf(-t*t)*EMBS;  t=q-7.f; eb7=__expf(-t*t)*EMBS;
        t=q-8.f; eb8=__expf(-t*t)*EMBS;  t=q-9.f; eb9=__expf(-t*t)*EMBS;
    }
    __syncthreads();
    float h[100];
#pragma unroll
    for (int k = 0; k < 100; ++k) {
        const float4 w0 = *(const float4*)&lR1[k*12];
        const float4 w1 = *(const float4*)&lR1[k*12 + 4];
        const float2 w2 = *(const float2*)&lR1[k*12 + 8];
        float a = eb0*w0.x + eb1*w0.y + eb2*w0.z + eb3*w0.w
                + eb4*w1.x + eb5*w1.y + eb6*w1.z + eb7*w1.w
                + eb8*w2.x + eb9*w2.y;
        h[k] = siluf(a*RS10);
    }
    const float* xsrow = xs1 + (size_t)src*S;
    const float* xvrow = (V > 0) ? (xv1 + (size_t)src*48) : xs1;
    float* msgrow = msg + (size_t)(p - p0)*WM;

    float mv0[16], mv1[16], mv2[16], tw[16], msg8[8];
#pragma unroll
    for (int w = 0; w < 16; ++w) { mv0[w]=0.f; mv1[w]=0.f; mv2[w]=0.f; tw[w]=0.f; }
#pragma unroll
    for (int j = 0; j < 8; ++j) msg8[j] = 0.f;

#pragma unroll 1
    for (int ch = 0; ch < NCH; ++ch) {
        const int c0 = ch*CHUNK;
        const int cw = (WOUT - c0) < CHUNK ? (WOUT - c0) : CHUNK;
        __syncthreads();
        for (int idx = threadIdx.x; idx < 100*cw; idx += 256) {
            int k = idx/cw, j = idx%cw;
            lR2[k*CHUNK + j] = R2[k*WOUT + c0 + j];
        }
        __syncthreads();
#pragma unroll 1
        for (int g = 0; g < cw/4; ++g) {
            const int j0 = c0 + 4*g;
            float a0=0.f, a1=0.f, a2=0.f, a3=0.f;
#pragma unroll
            for (int k = 0; k < 100; ++k) {
                const float4 w = *(const float4*)&lR2[k*CHUNK + 4*g];
                a0 += h[k]*w.x; a1 += h[k]*w.y; a2 += h[k]*w.z; a3 += h[k]*w.w;
            }
            a0 *= SR2; a1 *= SR2; a2 *= SR2; a3 *= SR2;
            if (valid) {
                if (j0 < O1) {                                    // w1: scalar msg
                    int u = j0 >> 2;
                    float dv = a0*es0 + a1*es1 + a2*es2 + a3*es3;
                    float v = 0.5f*xsrow[u]*dv;
                    if constexpr (FOLD) {
#pragma unroll
                        for (int j = 0; j < 8; ++j) msg8[j] += v*lWF[u*8 + j];
                    } else {
                        msgrow[u] = v;
                    }
                } else if (VEC_OUT && j0 < O2) {                  // w2: s->v msg (separable)
                    int u0 = j0 - O1;
                    float4 LA = *(const float4*)(xsrow + u0);
                    float m0 = LA.x*a0, m1 = LA.y*a1, m2 = LA.z*a2, m3 = LA.w*a3;
#pragma unroll
                    for (int w = 0; w < 16; ++w)
                        tw[w] += m0*lWF[(u0+0)*16+w] + m1*lWF[(u0+1)*16+w]
                               + m2*lWF[(u0+2)*16+w] + m3*lWF[(u0+3)*16+w];
                    if (j0 + 4 == O2) {                           // fold t*ev into mvp
#pragma unroll
                        for (int w = 0; w < 16; ++w) {
                            mv0[w] += tw[w]*ev0; mv1[w] += tw[w]*ev1; mv2[w] += tw[w]*ev2;
                        }
                    }
                } else if (V > 0 && VEC_OUT && j0 < O3) {         // w3: v->v msg
                    int u2 = (j0 - O2) >> 2;
                    const float* xp = xvrow + u2*3;
                    float dv = 0.5f*(a0*es0 + a1*es1 + a2*es2 + a3*es3);
                    float q0 = dv*xp[0], q1 = dv*xp[1], q2 = dv*xp[2];
#pragma unroll
                    for (int w = 0; w < 16; ++w) {
                        float wt = lWF[(S+u2)*16 + w];
                        mv0[w] += q0*wt; mv1[w] += q1*wt; mv2[w] += q2*wt;
                    }
                } else if (V > 0) {                               // w4: v->s msg
                    int u0 = j0 - O3;
                    const float4* pv = (const float4*)(xvrow + u0*3);
                    float4 A = pv[0], B = pv[1], C = pv[2];
                    float d0 = A.x*ev0 + A.y*ev1 + A.z*ev2;
                    float d1 = A.w*ev0 + B.x*ev1 + B.y*ev2;
                    float d2 = B.z*ev0 + B.w*ev1 + C.x*ev2;
                    float d3 = C.y*ev0 + C.z*ev1 + C.w*ev2;
                    float v0 = a0*d0*ISQ3, v1 = a1*d1*ISQ3, v2 = a2*d2*ISQ3, v3 = a3*d3*ISQ3;
                    if constexpr (FOLD) {
#pragma unroll
                        for (int j = 0; j < 8; ++j)
                            msg8[j] += v0*lWF[(S+u0+0)*8+j] + v1*lWF[(S+u0+1)*8+j]
                                     + v2*lWF[(S+u0+2)*8+j] + v3*lWF[(S+u0+3)*8+j];
                    } else {
                        msgrow[S+u0+0] = v0; msgrow[S+u0+1] = v1;
                        msgrow[S+u0+2] = v2; msgrow[S+u0+3] = v3;
                    }
                }
            }
        }
    }
    if (valid) {
        if constexpr (FOLD) {
            float4 f0 = {msg8[0], msg8[1], msg8[2], msg8[3]};
            float4 f1 = {msg8[4], msg8[5], msg8[6], msg8[7]};
            *(float4*)(msgrow+0) = f0;
            *(float4*)(msgrow+4) = f1;
        } else if constexpr (VEC_OUT) {
            // vec part layout: [c][w] (c-major), 48 floats after WMS scalars
#pragma unroll
            for (int w = 0; w < 16; w += 4) {
                float4 f0 = {mv0[w], mv0[w+1], mv0[w+2], mv0[w+3]};
                float4 f1 = {mv1[w], mv1[w+1], mv1[w+2], mv1[w+3]};
                float4 f2 = {mv2[w], mv2[w+1], mv2[w+2], mv2[w+3]};
                *(float4*)(msgrow + WMS + 0*16 + w) = f0;
                *(float4*)(msgrow + WMS + 1*16 + w) = f1;
                *(float4*)(msgrow + WMS + 2*16 + w) = f2;
            }
        }
    }
}

// ---------------------------------------------------------------- segmented sum
template<int W>
__global__ void k_segsum(const float* __restrict__ msg, float* __restrict__ Y,
                         const int* __restrict__ start, int p0, int p1)
{
    int idx = blockIdx.x*blockDim.x + threadIdx.x;
    if (idx >= NN*W) return;
    int n = idx / W;
    int c = idx - n*W;
    int lo = start[n], hi = start[n+1];
    if (lo < p0) lo = p0;
    if (hi > p1) hi = p1;
    if (lo >= hi) return;
    const float* q = msg + (size_t)(lo - p0)*W + c;
    float s = 0.f;
    for (int p = lo; p < hi; ++p) { s += *q; q += W; }
    Y[idx] += s;
}

// ---------------------------------------------------------------- node post + gate (in-place)
template<int SIN, int YSW, int WST, bool HASV>
__global__ void k_post(float* __restrict__ xsv, float* __restrict__ xvv,
                       const float* __restrict__ Y,
                       const float* __restrict__ scs, const float* __restrict__ scv,
                       const float* __restrict__ l2s,
                       float s_sc, float s_l2s, float s_scv, float s_l2v)
{
    __shared__ float Lscs[SIN*48];
    __shared__ float Ll2s[YSW*48];
    __shared__ float Lscv[HASV ? 256 : 1];
    for (int i = threadIdx.x; i < SIN*48; i += blockDim.x) Lscs[i] = scs[i];
    for (int i = threadIdx.x; i < YSW*48; i += blockDim.x) Ll2s[i] = l2s[i];
    if constexpr (HASV)
        for (int i = threadIdx.x; i < 256; i += blockDim.x) Lscv[i] = scv[i];
    __syncthreads();
    int n = blockIdx.x*blockDim.x + threadIdx.x;
    if (n >= NN) return;
    const float* yrow = Y + (size_t)n*WST;
    float xr[SIN];
#pragma unroll
    for (int u = 0; u < SIN; ++u) xr[u] = xsv[n*48 + u];
    float yr[YSW];
#pragma unroll
    for (int t = 0; t < YSW; ++t) yr[t] = yrow[t]*ISNN;
    float os[48];
    const float A = C_S*s_sc, B = C_X*s_l2s;
#pragma unroll
    for (int j = 0; j < 48; ++j) {
        float a = 0.f, b = 0.f;
#pragma unroll
        for (int u = 0; u < SIN; ++u) a += xr[u]*Lscs[u*48 + j];
#pragma unroll
        for (int t = 0; t < YSW; ++t) b += yr[t]*Ll2s[t*48 + j];
        os[j] = A*a + B*b;
    }
#pragma unroll
    for (int u = 0; u < 32; ++u) xsv[n*48 + u] = siluf(os[u]);
    float gg[16];
#pragma unroll
    for (int t = 0; t < 16; ++t) gg[t] = sigmf(os[32 + t]);
    // vec channel: pre-projected in edge kernel; just scale + combine + gate
    const float sc3 = ISNN*s_l2v*(HASV ? C_X : 1.0f);
    if constexpr (HASV) {
        float vr[48];
#pragma unroll
        for (int i = 0; i < 48; ++i) vr[i] = xvv[n*48 + i];
        const float Av = C_S*s_scv;
#pragma unroll
        for (int w = 0; w < 16; ++w) {
            float s0 = 0.f, s1 = 0.f, s2 = 0.f;
#pragma unroll
            for (int v = 0; v < 16; ++v) {
                float wt = Lscv[v*16 + w];
                s0 += vr[v*3+0]*wt; s1 += vr[v*3+1]*wt; s2 += vr[v*3+2]*wt;
            }
            xvv[n*48 + w*3 + 0] = (Av*s0 + sc3*yrow[YSW + 0*16 + w])*gg[w];
            xvv[n*48 + w*3 + 1] = (Av*s1 + sc3*yrow[YSW + 1*16 + w])*gg[w];
            xvv[n*48 + w*3 + 2] = (Av*s2 + sc3*yrow[YSW + 2*16 + w])*gg[w];
        }
    } else {
#pragma unroll
        for (int w = 0; w < 16; ++w) {
            xvv[n*48 + w*3 + 0] = sc3*yrow[YSW + 0*16 + w]*gg[w];
            xvv[n*48 + w*3 + 1] = sc3*yrow[YSW + 1*16 + w]*gg[w];
            xvv[n*48 + w*3 + 2] = sc3*yrow[YSW + 2*16 + w]*gg[w];
        }
    }
}

// ---------------------------------------------------------------- layer4 post + head
__global__ void k_final(const float* __restrict__ xsv, const float* __restrict__ Y8,
                        const float* __restrict__ scs,
                        const float* __restrict__ Wh, const float* __restrict__ bh,
                        float* __restrict__ out)
{
    __shared__ float Lscs[32*8];
    __shared__ float Lwh[24];
    __shared__ float Lbh[3];
    for (int i = threadIdx.x; i < 32*8; i += blockDim.x) Lscs[i] = scs[i];
    if (threadIdx.x < 24) Lwh[threadIdx.x] = Wh[threadIdx.x];
    if (threadIdx.x < 3)  Lbh[threadIdx.x] = bh[threadIdx.x];
    __syncthreads();
    int n = blockIdx.x*blockDim.x + threadIdx.x;
    if (n >= NN) return;
    float xr[32];
#pragma unroll
    for (int u = 0; u < 32; ++u) xr[u] = xsv[n*48 + u];
    const float CB = C_X*RS48*ISNN;
    float s8[8];
#pragma unroll
    for (int j = 0; j < 8; ++j) {
        float a = 0.f;
#pragma unroll
        for (int u = 0; u < 32; ++u) a += xr[u]*Lscs[u*8 + j];
        s8[j] = C_S*RS32*a + CB*Y8[n*8 + j];
    }
#pragma unroll
    for (int c = 0; c < 3; ++c) {
        float o = Lbh[c];
#pragma unroll
        for (int j = 0; j < 8; ++j) o += s8[j]*Lwh[j*3 + c];
        out[n*3 + c] = o;
    }
}

// ---------------------------------------------------------------- launcher
extern "C" void kernel_launch(void* const* d_in, const int* in_sizes, int n_in,
                              void* d_out, int out_size, void* d_ws, size_t ws_size,
                              hipStream_t stream)
{
    const float* pos       = (const float*)d_in[0];
    const float* onehot    = (const float*)d_in[1];
    const float* eattr     = (const float*)d_in[2];
    const float* W_embed   = (const float*)d_in[3];
    const float* b_embed   = (const float*)d_in[4];
    const float* l1_lin1_s = (const float*)d_in[5];
    const float* l1_sc_s   = (const float*)d_in[6];
    const float* l1_R1     = (const float*)d_in[7];
    const float* l1_R2     = (const float*)d_in[8];
    const float* l1_lin2_s = (const float*)d_in[9];
    const float* l1_lin2_v = (const float*)d_in[10];
    const float* l2_lin1_s = (const float*)d_in[11];
    const float* l2_lin1_v = (const float*)d_in[12];
    const float* l2_sc_s   = (const float*)d_in[13];
    const float* l2_sc_v   = (const float*)d_in[14];
    const float* l2_R1     = (const float*)d_in[15];
    const float* l2_R2     = (const float*)d_in[16];
    const float* l2_lin2_s = (const float*)d_in[17];
    const float* l2_lin2_v = (const float*)d_in[18];
    const float* l3_lin1_s = (const float*)d_in[19];
    const float* l3_lin1_v = (const float*)d_in[20];
    const float* l3_sc_s   = (const float*)d_in[21];
    const float* l3_sc_v   = (const float*)d_in[22];
    const float* l3_R1     = (const float*)d_in[23];
    const float* l3_R2     = (const float*)d_in[24];
    const float* l3_lin2_s = (const float*)d_in[25];
    const float* l3_lin2_v = (const float*)d_in[26];
    const float* l4_lin1_s = (const float*)d_in[27];
    const float* l4_lin1_v = (const float*)d_in[28];
    const float* l4_sc_s   = (const float*)d_in[29];
    const float* l4_R1     = (const float*)d_in[30];
    const float* l4_R2     = (const float*)d_in[31];
    const float* l4_lin2_s = (const float*)d_in[32];
    const float* W_head    = (const float*)d_in[33];
    const float* b_head    = (const float*)d_in[34];
    const int*   eidx      = (const int*)d_in[35];
    const int* srcv = eidx;
    const int* dstv = eidx + NE;

    float* ws = (float*)d_ws;
    size_t off = 0;
    float* XS    = ws + off; off += 48ull*NN;
    float* XV    = ws + off; off += 48ull*NN;
    float* XS1   = ws + off; off += 32ull*NN;
    float* XV1   = ws + off; off += 48ull*NN;
    float* Y     = ws + off; off += 96ull*NN;
    int*   start = (int*)(ws + off); off += NN + 1;
    int*   cursor= (int*)(ws + off); off += NN;
    int*   perm  = (int*)(ws + off); off += NE;
    float* MSG   = ws + off;
    size_t totalFloats = ws_size/4;
    size_t msgCap = (totalFloats > off) ? (totalFloats - off) : 0;

    dim3 th(256), be((NE + 255)/256), bn((NN + 255)/256);

    // ---- build dst-sorted permutation (once)
    hipMemsetAsync(cursor, 0, NN*sizeof(int), stream);
    k_hist<<<be, th, 0, stream>>>(dstv, cursor);
    k_scan<<<1, 1024, 0, stream>>>(cursor, start);
    k_scatter<<<be, th, 0, stream>>>(dstv, cursor, perm);

    k_embed<<<bn, th, 0, stream>>>(onehot, W_embed, b_embed, XS);

    // chunked edge-msg + segsum driver (width WM known per layer)
    auto chunks = [&](int WM) {
        long ec = (WM > 0 && msgCap > 0) ? (long)(msgCap / (size_t)WM) : NE;
        if (ec > NE) ec = NE;
        if (ec < 4096) ec = 4096;   // safety floor
        return ec;
    };

    // ---- layer 1 (S=16, V=0, WOUT=80, vec_out; msg width 64 = 16 + 48)
    {
        k_pre<16,16,0><<<bn, th, 0, stream>>>(XS, nullptr, l1_lin1_s, nullptr, XS1, XV1, RS16, RS16);
        hipMemsetAsync(Y, 0, 64ull*NN*sizeof(float), stream);
        long EC = chunks(64);
        for (long c0 = 0; c0 < NE; c0 += EC) {
            int p0 = (int)c0, p1 = (int)((c0 + EC < NE) ? c0 + EC : NE);
            dim3 ge(((p1-p0) + 255)/256);
            k_edgemsg<16,0,80,true,1,64,16,false><<<ge, th, 0, stream>>>(
                pos, eattr, srcv, dstv, perm, XS1, XV1, l1_R1, l1_R2, l1_lin2_v, MSG, p0, p1);
            dim3 gs((NN*64 + 255)/256);
            k_segsum<64><<<gs, th, 0, stream>>>(MSG, Y, start, p0, p1);
        }
        k_post<16,16,64,false><<<bn, th, 0, stream>>>(XS, XV, Y, l1_sc_s, nullptr, l1_lin2_s,
                                                      RS16, RS16, 0.f, RS16);
    }

    // ---- layers 2,3 (S=32, V=16, WOUT=240, vec_out; msg width 96 = 48 + 48)
    const float* L2w[2][6] = {
        {l2_lin1_s, l2_lin1_v, l2_R1, l2_R2, l2_lin2_v, l2_lin2_s},
        {l3_lin1_s, l3_lin1_v, l3_R1, l3_R2, l3_lin2_v, l3_lin2_s}};
    const float* L2sc[2][2] = {{l2_sc_s, l2_sc_v}, {l3_sc_s, l3_sc_v}};
    for (int L = 0; L < 2; ++L) {
        k_pre<32,32,16><<<bn, th, 0, stream>>>(XS, XV, L2w[L][0], L2w[L][1], XS1, XV1, RS32, RS16);
        hipMemsetAsync(Y, 0, 96ull*NN*sizeof(float), stream);
        long EC = chunks(96);
        for (long c0 = 0; c0 < NE; c0 += EC) {
            int p0 = (int)c0, p1 = (int)((c0 + EC < NE) ? c0 + EC : NE);
            dim3 ge(((p1-p0) + 255)/256);
            k_edgemsg<32,16,240,true,3,96,48,false><<<ge, th, 0, stream>>>(
                pos, eattr, srcv, dstv, perm, XS1, XV1, L2w[L][2], L2w[L][3], L2w[L][4], MSG, p0, p1);
            dim3 gs((NN*96 + 255)/256);
            k_segsum<96><<<gs, th, 0, stream>>>(MSG, Y, start, p0, p1);
        }
        k_post<32,48,96,true><<<bn, th, 0, stream>>>(XS, XV, Y, L2sc[L][0], L2sc[L][1], L2w[L][5],
                                                     RS32, RS48, RS16, RS48);
    }

    // ---- layer 4 (S=32, V=16, WOUT=144, no vec_out; lin2_s folded -> msg width 8)
    {
        k_pre<32,32,16><<<bn, th, 0, stream>>>(XS, XV, l4_lin1_s, l4_lin1_v, XS1, XV1, RS32, RS16);
        hipMemsetAsync(Y, 0, 8ull*NN*sizeof(float), stream);
        long EC = chunks(8);
        for (long c0 = 0; c0 < NE; c0 += EC) {
            int p0 = (int)c0, p1 = (int)((c0 + EC < NE) ? c0 + EC : NE);
            dim3 ge(((p1-p0) + 255)/256);
            k_edgemsg<32,16,144,false,2,8,48,true><<<ge, th, 0, stream>>>(
                pos, eattr, srcv, dstv, perm, XS1, XV1, l4_R1, l4_R2, l4_lin2_s, MSG, p0, p1);
            dim3 gs((NN*8 + 255)/256);
            k_segsum<8><<<gs, th, 0, stream>>>(MSG, Y, start, p0, p1);
        }
        k_final<<<bn, th, 0, stream>>>(XS, Y, l4_sc_s, W_head, b_head, (float*)d_out);
    }
}